// Round 1
// baseline (160.154 us; speedup 1.0000x reference)
//
#include <hip/hip_runtime.h>

#define T_DIM 4096
#define E_DIM 64
#define WIN   128
#define NWIN  (T_DIM / WIN)   // 32 windows
#define VT_LD 264             // padded LD for transposed V tile (bf16)
#define PS_LD 36              // padded LD for per-wave P scratch (bf16)

typedef __bf16  bf16x8 __attribute__((ext_vector_type(8)));
typedef __bf16  bf16x4 __attribute__((ext_vector_type(4)));
typedef float   f32x16 __attribute__((ext_vector_type(16)));

// One block per (bh, window): 256 threads = 4 waves, wave w owns query rows [32w,32w+32).
// S=QK^T and O=PV via mfma_f32_32x32x16_bf16.
// Verified layouts (learn_hip m74/m101): C/D: col=lane&31, row=(reg&3)+8*(reg>>2)+4*(lane>>5)
//   A: A[m=lane&31][k=(lane>>5)*8+j]   B: B[k=(lane>>5)*8+j][n=lane&31]
__global__ __launch_bounds__(256, 2)
void la_fwd(const float* __restrict__ Q, const float* __restrict__ K,
            const float* __restrict__ V, float* __restrict__ O)
{
  __shared__ __bf16 Vt[E_DIM * VT_LD];      // V^T tile: Vt[e][j] = V[k0+j][e], 33792 B
  __shared__ __bf16 Ps[4 * 32 * PS_LD];     // per-wave P scratch, 9216 B

  const int tid  = threadIdx.x;
  const int lane = tid & 63;
  const int wid  = tid >> 6;     // wave id 0..3
  const int col  = lane & 31;    // MFMA n / C-col
  const int half = lane >> 5;    // MFMA k-half select

  const int w  = blockIdx.x;     // window 0..31
  const int bh = blockIdx.y;     // 0..31

  const float* Qb = Q + (size_t)bh * T_DIM * E_DIM;
  const float* Kb = K + (size_t)bh * T_DIM * E_DIM;
  const float* Vb = V + (size_t)bh * T_DIM * E_DIM;
  float*       Ob = O + (size_t)bh * T_DIM * E_DIM;

  const int q0 = w * WIN;        // first query row of this window
  const int k0 = (w - 1) * WIN;  // first (global) key row; negative for w==0 (masked)

  // ---- stage V^T into LDS as bf16 (thread-per-row: LDS writes ~2-way = free) ----
  {
    const int j = tid;                       // key slot 0..255
    int jg = k0 + j; if (jg < 0) jg = 0;     // clamped rows are fully masked later
    const float* vrow = Vb + (size_t)jg * E_DIM;
#pragma unroll
    for (int c4 = 0; c4 < 16; ++c4) {
      const float4 vv = *(const float4*)(vrow + c4 * 4);
      const int e = c4 * 4;
      Vt[(e + 0) * VT_LD + j] = (__bf16)vv.x;
      Vt[(e + 1) * VT_LD + j] = (__bf16)vv.y;
      Vt[(e + 2) * VT_LD + j] = (__bf16)vv.z;
      Vt[(e + 3) * VT_LD + j] = (__bf16)vv.w;
    }
  }

  // ---- Q A-fragments straight from global, scale*log2(e) folded in ----
  const float QS = 0.125f * 1.44269504088896340736f;  // e^-0.5 * log2(e)
  bf16x8 aq[4];
  {
    const float* qrow = Qb + (size_t)(q0 + wid * 32 + col) * E_DIM;
#pragma unroll
    for (int c = 0; c < 4; ++c) {
      const float* p = qrow + c * 16 + half * 8;
      const float4 x = *(const float4*)(p);
      const float4 y = *(const float4*)(p + 4);
      bf16x8 a;
      a[0] = (__bf16)(x.x * QS); a[1] = (__bf16)(x.y * QS);
      a[2] = (__bf16)(x.z * QS); a[3] = (__bf16)(x.w * QS);
      a[4] = (__bf16)(y.x * QS); a[5] = (__bf16)(y.y * QS);
      a[6] = (__bf16)(y.z * QS); a[7] = (__bf16)(y.w * QS);
      aq[c] = a;
    }
  }

  __syncthreads();  // Vt visible to all waves before PV phase

  // ---- S = Q K^T : 8 key-blocks of 32, K B-frags from global (L1/L2 reuse) ----
  f32x16 sacc[8];
#pragma unroll
  for (int kb = 0; kb < 8; ++kb)
#pragma unroll
    for (int r = 0; r < 16; ++r) sacc[kb][r] = 0.0f;

#pragma unroll
  for (int kb = 0; kb < 8; ++kb) {
    int jg = k0 + kb * 32 + col; if (jg < 0) jg = 0;
    const float* krow = Kb + (size_t)jg * E_DIM;
#pragma unroll
    for (int c = 0; c < 4; ++c) {
      const float* p = krow + c * 16 + half * 8;
      const float4 x = *(const float4*)(p);
      const float4 y = *(const float4*)(p + 4);
      bf16x8 b;
      b[0] = (__bf16)x.x; b[1] = (__bf16)x.y; b[2] = (__bf16)x.z; b[3] = (__bf16)x.w;
      b[4] = (__bf16)y.x; b[5] = (__bf16)y.y; b[6] = (__bf16)y.z; b[7] = (__bf16)y.w;
      sacc[kb] = __builtin_amdgcn_mfma_f32_32x32x16_bf16(aq[c], b, sacc[kb], 0, 0, 0);
    }
  }

  // ---- masked softmax over 256 keys (log2 domain; row lives in one 32-lane half) ----
  float rinv[16];
#pragma unroll
  for (int r = 0; r < 16; ++r) {
    const int row  = (r & 3) + 8 * (r >> 2) + 4 * half;
    const int iloc = wid * 32 + row;           // query index within window
    float m = -3.0e38f;
#pragma unroll
    for (int kb = 0; kb < 8; ++kb) {
      const int jloc = kb * 32 + col;          // key index within 256-window
      // causal: key_global > q_global  <=>  jloc > iloc+128 ; pad: w==0 && jloc<128
      const bool masked = (jloc > iloc + WIN) || (w == 0 && jloc < WIN);
      const float s = masked ? -3.0e38f : sacc[kb][r];
      sacc[kb][r] = s;
      m = fmaxf(m, s);
    }
#pragma unroll
    for (int d = 1; d <= 16; d <<= 1) m = fmaxf(m, __shfl_xor(m, d));
    float l = 0.0f;
#pragma unroll
    for (int kb = 0; kb < 8; ++kb) {
      const float p = __builtin_amdgcn_exp2f(sacc[kb][r] - m);  // masked -> exp2(-inf)=0
      sacc[kb][r] = p;
      l += p;
    }
#pragma unroll
    for (int d = 1; d <= 16; d <<= 1) l += __shfl_xor(l, d);
    rinv[r] = __builtin_amdgcn_rcpf(l);
  }

  // ---- O = P V : C-layout -> A-layout via per-wave LDS scratch; V^T B-frags ----
  f32x16 oacc[2];
#pragma unroll
  for (int et = 0; et < 2; ++et)
#pragma unroll
    for (int r = 0; r < 16; ++r) oacc[et][r] = 0.0f;

  __bf16* myPs = Ps + wid * (32 * PS_LD);
#pragma unroll
  for (int kb = 0; kb < 8; ++kb) {
#pragma unroll
    for (int r = 0; r < 16; ++r) {
      const int row = (r & 3) + 8 * (r >> 2) + 4 * half;
      myPs[row * PS_LD + col] = (__bf16)sacc[kb][r];
    }
    // same-wave RAW through LDS: in-order DS + compiler waitcnt, no barrier needed
    bf16x8 ap[2];
#pragma unroll
    for (int c2 = 0; c2 < 2; ++c2) {
      const __bf16* rp = myPs + col * PS_LD + c2 * 16 + half * 8;  // 8B-aligned
      union { bf16x8 v8; bf16x4 v4[2]; } u;
      u.v4[0] = *(const bf16x4*)(rp);
      u.v4[1] = *(const bf16x4*)(rp + 4);
      ap[c2] = u.v8;
    }
#pragma unroll
    for (int c2 = 0; c2 < 2; ++c2) {
      const int j0 = kb * 32 + c2 * 16 + half * 8;
#pragma unroll
      for (int et = 0; et < 2; ++et) {
        const int e = et * 32 + col;
        const bf16x8 bv = *(const bf16x8*)(Vt + e * VT_LD + j0);  // 16B-aligned
        oacc[et] = __builtin_amdgcn_mfma_f32_32x32x16_bf16(ap[c2], bv, oacc[et], 0, 0, 0);
      }
    }
  }

  // ---- epilogue: normalize and store (coalesced 128B half-wave segments) ----
#pragma unroll
  for (int r = 0; r < 16; ++r) {
    const int row = (r & 3) + 8 * (r >> 2) + 4 * half;
    const int ig  = q0 + wid * 32 + row;
    float* op = Ob + (size_t)ig * E_DIM;
    op[col]      = oacc[0][r] * rinv[r];
    op[col + 32] = oacc[1][r] * rinv[r];
  }
}

extern "C" void kernel_launch(void* const* d_in, const int* in_sizes, int n_in,
                              void* d_out, int out_size, void* d_ws, size_t ws_size,
                              hipStream_t stream) {
  const float* Q = (const float*)d_in[0];
  const float* K = (const float*)d_in[1];
  const float* V = (const float*)d_in[2];
  float*       O = (float*)d_out;
  const int bh = in_sizes[0] / (T_DIM * E_DIM);   // 32 for (2,16,4096,64)
  dim3 grid(NWIN, bh);
  la_fwd<<<grid, 256, 0, stream>>>(Q, K, V, O);
}